// Round 19
// baseline (1051.469 us; speedup 1.0000x reference)
//
#include <hip/hip_runtime.h>
#include <hip/hip_bf16.h>
#include <hip/hip_fp16.h>
#include <cstdint>
#include <cstddef>

// Problem constants
#define B_    4
#define L_    2048
#define DIM_  512
#define DI_   1024          // d_inner
#define M_    (B_ * L_)     // 8192 rows
#define DSTATE 16
#define DTR   32
#define TCH   32            // scan chunk length (proven config)
#define NCH   (L_ / TCH)    // 64 chunks
#define KSP   8             // GEMM2 K-split
#define KCH   (DI_ / KSP)   // 128

typedef __attribute__((ext_vector_type(8))) _Float16 f16x8;   // 8 f16 = 4 VGPRs
typedef __attribute__((ext_vector_type(4))) float f32x4;

#define LOG2E 1.44269504088896340736f

__device__ __forceinline__ float sigmoidf_(float x) { return 1.f / (1.f + expf(-x)); }
__device__ __forceinline__ float softplusf_(float x) { return fmaxf(x, 0.f) + log1pf(expf(-fabsf(x))); }
// fast-trans softplus via HIP device intrinsics (v_exp_f32 / v_log_f32 path)
__device__ __forceinline__ float softplus_fast(float x) {
    return fmaxf(x, 0.f) + __logf(1.f + __expf(-fabsf(x)));
}

// pw[n] = e1^(n+1), n=0..15, via log-depth product tree (15 muls, depth<=5)
__device__ __forceinline__ void pow_chain16(float e1, float* pw) {
    pw[0] = e1;
#pragma unroll
    for (int k = 2; k <= 16; ++k) pw[k - 1] = pw[k / 2 - 1] * pw[k - k / 2 - 1];
}

// fp32 -> fp16 bulk conversion (4 elems/thread)
__global__ __launch_bounds__(256) void tofp16_k(const float* __restrict__ in,
                                                _Float16* __restrict__ out, int n)
{
    const int i = (blockIdx.x * 256 + threadIdx.x) * 4;
    if (i < n) {
        const float4 v = *(const float4*)(in + i);
        _Float16 o[4] = { (_Float16)v.x, (_Float16)v.y, (_Float16)v.z, (_Float16)v.w };
        *(ushort4*)(out + i) = *(const ushort4*)o;
    }
}

// ---- fp16 MFMA GEMM, templated BK (barrier count vs LDS/occupancy tradeoff).
// SPLIT=1 (GEMM1, N=2048, BK=64): cols < DI_ -> fp16 Cx, cols >= DI_ -> fp16 Cz.
// SPLIT=2 (GEMM4, split-K=2, BK=32): blockIdx.z = ks selects K-half; fp32 partial
//   to C + ks*M_*DIM_. XCD-aware swizzle on x-y (nwg % 8 == 0 for both uses).
// Staging: 1024 B chunks; chunk covers RPC rows x BK cols; lane l -> row l/LPC,
//   k-elem (l%LPC)*8 (linear global_load_lds dest: byte l*16).
#define GBM 128
#define GBN 128
template <int SPLIT, int BK>
__global__ __launch_bounds__(256) void gemm_f16_nt(const _Float16* __restrict__ A, int lda,
                                                   const _Float16* __restrict__ W, int ldw,
                                                   float* __restrict__ C, int ldc, int K,
                                                   _Float16* __restrict__ Cx,
                                                   _Float16* __restrict__ Cz)
{
    __shared__ _Float16 As[GBM][BK];
    __shared__ _Float16 Ws[GBN][BK];
    const int tid = threadIdx.x;
    const int wv = tid >> 6, ln = tid & 63;

    constexpr int LPC = BK / 8;             // lanes per row (16 B per lane)
    constexpr int RPC = 64 / LPC;           // rows per 1024 B chunk
    constexpr int CPW = (GBM / RPC) / 4;    // chunks per wave

    if (SPLIT == 2) {
        const int ks = blockIdx.z;
        A += (size_t)ks * 512;            // k-offset within row (lda unchanged)
        W += (size_t)ks * 512;
        C += (size_t)ks * (size_t)M_ * DIM_;
    }

    // XCD swizzle: contiguous chunk of flattened block ids per XCD (L2 locality)
    const int gx = gridDim.x;
    const int nwg = gx * gridDim.y;
    int bid = blockIdx.y * gx + blockIdx.x;
    bid = (bid & 7) * (nwg >> 3) + (bid >> 3);
    const int bx = bid % gx, by = bid / gx;

    const int m0 = by * GBM, n0 = bx * GBN;
    const int wm = (wv >> 1) * 64, wn = (wv & 1) * 64;

    const int c0 = wv * CPW;
    const int srow0 = c0 * RPC + (ln / LPC);
    const int skcol = (ln % LPC) * 8;

    const int fr = ln & 15;
    const int fk = (ln >> 4) * 8;

    f32x4 acc[4][4] = {};

    for (int k0 = 0; k0 < K; k0 += BK) {
#pragma unroll
        for (int i = 0; i < CPW; ++i) {
            const int c = c0 + i;
            const int row = srow0 + i * RPC;
            __builtin_amdgcn_global_load_lds(
                (const __attribute__((address_space(1))) void*)(A + (size_t)(m0 + row) * lda + k0 + skcol),
                (__attribute__((address_space(3))) void*)((char*)&As[0][0] + c * 1024), 16, 0, 0);
            __builtin_amdgcn_global_load_lds(
                (const __attribute__((address_space(1))) void*)(W + (size_t)(n0 + row) * ldw + k0 + skcol),
                (__attribute__((address_space(3))) void*)((char*)&Ws[0][0] + c * 1024), 16, 0, 0);
        }
        __syncthreads();

#pragma unroll
        for (int kk = 0; kk < BK; kk += 32) {
            f16x8 aF[4], bF[4];
#pragma unroll
            for (int m = 0; m < 4; ++m) aF[m] = *(const f16x8*)&As[wm + m * 16 + fr][kk + fk];
#pragma unroll
            for (int n = 0; n < 4; ++n) bF[n] = *(const f16x8*)&Ws[wn + n * 16 + fr][kk + fk];
#pragma unroll
            for (int m = 0; m < 4; ++m)
#pragma unroll
                for (int n = 0; n < 4; ++n)
                    acc[m][n] = __builtin_amdgcn_mfma_f32_16x16x32_f16(aF[m], bF[n], acc[m][n], 0, 0, 0);
        }
        __syncthreads();
    }

    const int cr = (ln >> 4) * 4;
    const int cc = ln & 15;
#pragma unroll
    for (int m = 0; m < 4; ++m)
#pragma unroll
        for (int n = 0; n < 4; ++n)
#pragma unroll
            for (int r = 0; r < 4; ++r) {
                const int mm = m0 + wm + m * 16 + cr + r;
                const int nn = n0 + wn + n * 16 + cc;
                if (SPLIT == 1) {
                    if (n0 < DI_) Cx[(size_t)mm * DI_ + nn] = (_Float16)acc[m][n][r];
                    else          Cz[(size_t)mm * DI_ + (nn - DI_)] = (_Float16)acc[m][n][r];
                } else {
                    C[(size_t)mm * ldc + nn] = acc[m][n][r];
                }
            }
}

// ---- GEMM2 split-K: P[ks][M][64] = xih[M x 1024] * Wx[64 x 1024]^T over K-chunk ks.
__global__ __launch_bounds__(256) void gemm2_f16_splitk(const _Float16* __restrict__ A,
                                                        const _Float16* __restrict__ W,
                                                        float* __restrict__ P)
{
    __shared__ _Float16 As[64][32];   // 4 KB
    __shared__ _Float16 Ws[64][32];   // 4 KB
    const int tid = threadIdx.x;
    const int wv = tid >> 6, ln = tid & 63;
    const int ks = blockIdx.x;
    const int m0 = blockIdx.y * 64;
    const int srow = wv * 16 + (ln >> 2);
    const int skcol = (ln & 3) * 8;
    const int fr = ln & 15, fk = (ln >> 4) * 8;
    f32x4 acc[4] = {};

    for (int k0 = ks * KCH; k0 < ks * KCH + KCH; k0 += 32) {
        __builtin_amdgcn_global_load_lds(
            (const __attribute__((address_space(1))) void*)(A + (size_t)(m0 + srow) * DI_ + k0 + skcol),
            (__attribute__((address_space(3))) void*)((char*)&As[0][0] + wv * 1024), 16, 0, 0);
        __builtin_amdgcn_global_load_lds(
            (const __attribute__((address_space(1))) void*)(W + (size_t)srow * DI_ + k0 + skcol),
            (__attribute__((address_space(3))) void*)((char*)&Ws[0][0] + wv * 1024), 16, 0, 0);
        __syncthreads();
        const f16x8 aF = *(const f16x8*)&As[wv * 16 + fr][fk];
#pragma unroll
        for (int nf = 0; nf < 4; ++nf) {
            const f16x8 bF = *(const f16x8*)&Ws[nf * 16 + fr][fk];
            acc[nf] = __builtin_amdgcn_mfma_f32_16x16x32_f16(aF, bF, acc[nf], 0, 0, 0);
        }
        __syncthreads();
    }

    const int cr = (ln >> 4) * 4, cc = ln & 15;
    float* Pb = P + (size_t)ks * M_ * 64;
#pragma unroll
    for (int nf = 0; nf < 4; ++nf)
#pragma unroll
        for (int r = 0; r < 4; ++r)
            Pb[(size_t)(m0 + wv * 16 + cr + r) * 64 + nf * 16 + cc] = acc[nf][r];
}

// Fixed-order partial reduction: dbl = sum_ks P[ks]; dt-rank half also as fp16.
__global__ __launch_bounds__(256) void gemm2_reduce_k(const float* __restrict__ P,
                                                      float* __restrict__ dbl,
                                                      _Float16* __restrict__ dblh)
{
    const int i = (blockIdx.x * 256 + threadIdx.x) * 4;  // over M_*64
    float4 s = *(const float4*)&P[i];
#pragma unroll
    for (int ks = 1; ks < KSP; ++ks) {
        const float4 v = *(const float4*)&P[(size_t)ks * M_ * 64 + i];
        s.x += v.x; s.y += v.y; s.z += v.z; s.w += v.w;
    }
    *(float4*)&dbl[i] = s;
    const int col = i & 63;
    if (col < DTR) {
        const int row = i >> 6;
        _Float16 o[4] = { (_Float16)s.x, (_Float16)s.y, (_Float16)s.z, (_Float16)s.w };
        *(ushort4*)&dblh[(size_t)row * DTR + col] = *(const ushort4*)o;
    }
}

// ---- GEMM3 fp16 MFMA: dth[M x 1024] = softplus(dblh[M x 32] * Wdth^T + bdt), fp16 out.
__global__ __launch_bounds__(256) void gemm3_f16(const _Float16* __restrict__ A,
                                                 const _Float16* __restrict__ W,
                                                 const float* __restrict__ bias,
                                                 _Float16* __restrict__ Cout)
{
    __shared__ _Float16 As[64][32];   // 4 KB
    __shared__ _Float16 Ws[64][32];   // 4 KB
    const int tid = threadIdx.x;
    const int wv = tid >> 6, ln = tid & 63;
    const int m0 = blockIdx.y * 64, n0 = blockIdx.x * 64;
    const int srow = wv * 16 + (ln >> 2);
    const int skcol = (ln & 3) * 8;
    const int fr = ln & 15, fk = (ln >> 4) * 8;

    __builtin_amdgcn_global_load_lds(
        (const __attribute__((address_space(1))) void*)(A + (size_t)(m0 + srow) * DTR + skcol),
        (__attribute__((address_space(3))) void*)((char*)&As[0][0] + wv * 1024), 16, 0, 0);
    __builtin_amdgcn_global_load_lds(
        (const __attribute__((address_space(1))) void*)(W + (size_t)(n0 + srow) * DTR + skcol),
        (__attribute__((address_space(3))) void*)((char*)&Ws[0][0] + wv * 1024), 16, 0, 0);
    __syncthreads();

    const f16x8 aF = *(const f16x8*)&As[wv * 16 + fr][fk];
    f32x4 acc[4] = {};
#pragma unroll
    for (int nf = 0; nf < 4; ++nf) {
        const f16x8 bF = *(const f16x8*)&Ws[nf * 16 + fr][fk];
        acc[nf] = __builtin_amdgcn_mfma_f32_16x16x32_f16(aF, bF, acc[nf], 0, 0, 0);
    }

    const int cr = (ln >> 4) * 4, cc = ln & 15;
    const int mmb = m0 + wv * 16 + cr;
#pragma unroll
    for (int nf = 0; nf < 4; ++nf) {
        const int nn = n0 + nf * 16 + cc;
        const float bs = bias[nn];
#pragma unroll
        for (int r = 0; r < 4; ++r)
            Cout[(size_t)(mmb + r) * DI_ + nn] = (_Float16)softplus_fast(acc[nf][r] + bs);
    }
}

// depthwise causal conv(4) + bias + SiLU, vectorized: 8 consecutive d per thread.
__global__ __launch_bounds__(256) void conv_silu_k(const _Float16* __restrict__ xch,
                                                   const float* __restrict__ cw,
                                                   const float* __restrict__ cb,
                                                   _Float16* __restrict__ xih)
{
    const int idx = (blockIdx.x * 256 + threadIdx.x) * 8;   // over M_*DI_
    const int d0  = idx & (DI_ - 1);
    const int bt  = idx >> 10;                               // b*L + t
    const int t   = bt & (L_ - 1);

    float xr[4][8];
#pragma unroll
    for (int j = 0; j < 4; ++j) {
        const int tt = t - 3 + j;
        if (tt >= 0) {
            const f16x8 xv = *(const f16x8*)&xch[(size_t)(bt - 3 + j) * DI_ + d0];
#pragma unroll
            for (int i = 0; i < 8; ++i) xr[j][i] = (float)xv[i];
        } else {
#pragma unroll
            for (int i = 0; i < 8; ++i) xr[j][i] = 0.f;
        }
    }

    _Float16 o[8];
#pragma unroll
    for (int i = 0; i < 8; ++i) {
        const float4 w = *(const float4*)&cw[(size_t)(d0 + i) * 4];
        float a = cb[d0 + i] + w.x * xr[0][i] + w.y * xr[1][i]
                             + w.z * xr[2][i] + w.w * xr[3][i];
        o[i] = (_Float16)(a * sigmoidf_(a));
    }
    *(f16x8*)&xih[idx] = *(const f16x8*)&o[0];
}

// ---- Chunked parallel scan, register-state, 1 channel per thread ---------
__device__ __forceinline__ bool chain_ok(const float* Arow, float A0l2) {
    bool ok = true;
#pragma unroll
    for (int n = 1; n < 16; ++n) {
        const float an = -expf(Arow[n]) * LOG2E;
        ok = ok && (fabsf(an - (float)(n + 1) * A0l2) <= 1e-4f * fabsf(an));
    }
    return ok;
}

__device__ __forceinline__ void store16h(_Float16* dst, const float* src) {
    _Float16 t[16];
#pragma unroll
    for (int n = 0; n < 16; ++n) t[n] = (_Float16)src[n];
    *(f16x8*)&dst[0] = *(const f16x8*)&t[0];
    *(f16x8*)&dst[8] = *(const f16x8*)&t[8];
}
__device__ __forceinline__ void load16h(float* dst, const _Float16* src) {
    _Float16 t[16];
    *(f16x8*)&t[0] = *(const f16x8*)&src[0];
    *(f16x8*)&t[8] = *(const f16x8*)&src[8];
#pragma unroll
    for (int n = 0; n < 16; ++n) dst[n] = (float)t[n];
}

__global__ __launch_bounds__(256) void scan_chunk_k(const _Float16* __restrict__ dth,
                                                    const _Float16* __restrict__ xih,
                                                    const float* __restrict__ dbl,
                                                    const float* __restrict__ A_log,
                                                    _Float16* __restrict__ hloc,
                                                    _Float16* __restrict__ prod)
{
    const int tid = threadIdx.x;
    const int d = blockIdx.x * 256 + tid;
    const int c = blockIdx.y, b = blockIdx.z;
    __shared__ float BC[TCH][32];
    const size_t bt0 = (size_t)b * L_ + c * TCH;
    {   // stage TCH rows x 32 floats (256 threads cover 32x8 float4s)
        const int tl = tid >> 3;
        const int fo = (tid & 7) * 4;
        *(float4*)&BC[tl][fo] = *(const float4*)&dbl[(bt0 + tl) * 64 + DTR + fo];
    }
    const float A0 = -expf(A_log[d * DSTATE]) * LOG2E;
    const bool ch = chain_ok(A_log + d * DSTATE, A0);
    __syncthreads();

    float h[16] = {};
    float sdt = 0.f;
    if (ch) {
        for (int t = 0; t < TCH; ++t) {
            const size_t bt = bt0 + t;
            const float dtv = (float)dth[bt * DI_ + d];
            const float xiv = (float)xih[bt * DI_ + d];
            const float w = dtv * xiv;
            sdt += dtv;
            float Bv[16];
#pragma unroll
            for (int n = 0; n < 16; n += 4) *(float4*)&Bv[n] = *(const float4*)&BC[t][n];
            float pw[16];
            pow_chain16(exp2f(dtv * A0), pw);
#pragma unroll
            for (int n = 0; n < 16; ++n)
                h[n] = pw[n] * h[n] + w * Bv[n];
        }
        const size_t o = (((size_t)b * DI_ + d) * NCH + c) * DSTATE;
        float e[16];
        pow_chain16(exp2f(A0 * sdt), e);
        store16h(&hloc[o], h); store16h(&prod[o], e);
    } else {
        float An[16];
#pragma unroll
        for (int n = 0; n < 16; ++n)
            An[n] = -expf(A_log[d * DSTATE + n]) * LOG2E;
        for (int t = 0; t < TCH; ++t) {
            const size_t bt = bt0 + t;
            const float dtv = (float)dth[bt * DI_ + d];
            const float xiv = (float)xih[bt * DI_ + d];
            const float w = dtv * xiv;
            sdt += dtv;
            float Bv[16];
#pragma unroll
            for (int n = 0; n < 16; n += 4) *(float4*)&Bv[n] = *(const float4*)&BC[t][n];
#pragma unroll
            for (int n = 0; n < 16; ++n)
                h[n] = exp2f(dtv * An[n]) * h[n] + w * Bv[n];
        }
        const size_t o = (((size_t)b * DI_ + d) * NCH + c) * DSTATE;
        float e[16];
#pragma unroll
        for (int n = 0; n < 16; ++n) e[n] = exp2f(An[n] * sdt);
        store16h(&hloc[o], h); store16h(&prod[o], e);
    }
}

// Phase 2: sequential combine over chunks, 4-deep load pipelining (fp16 IO, fp32 math).
__global__ __launch_bounds__(256) void scan_carry_k(_Float16* __restrict__ hloc,
                                                    const _Float16* __restrict__ prod)
{
    const int idx = blockIdx.x * 256 + threadIdx.x;  // over B_*DI_*DSTATE
    const int n = idx & 15;
    const int d = (idx >> 4) & (DI_ - 1);
    const int b = idx >> 14;
    const size_t base = (((size_t)b * DI_ + d) * NCH) * DSTATE + n;
    float hl[4], pr[4], hn[4], pn[4];
#pragma unroll
    for (int j = 0; j < 4; ++j) {
        hl[j] = (float)hloc[base + (size_t)j * DSTATE];
        pr[j] = (float)prod[base + (size_t)j * DSTATE];
    }
    float carry = 0.f;
    for (int c0 = 0; c0 < NCH; c0 += 4) {
        if (c0 + 4 < NCH) {
#pragma unroll
            for (int j = 0; j < 4; ++j) {
                hn[j] = (float)hloc[base + (size_t)(c0 + 4 + j) * DSTATE];
                pn[j] = (float)prod[base + (size_t)(c0 + 4 + j) * DSTATE];
            }
        }
#pragma unroll
        for (int j = 0; j < 4; ++j) {
            hloc[base + (size_t)(c0 + j) * DSTATE] = (_Float16)carry;
            carry = hl[j] + pr[j] * carry;
        }
#pragma unroll
        for (int j = 0; j < 4; ++j) { hl[j] = hn[j]; pr[j] = pn[j]; }
    }
}

// Phase 3: re-scan from true initial state; y = (h·C + xi*D)*silu(z) as fp16.
__global__ __launch_bounds__(256) void scan_apply_k(const _Float16* __restrict__ dth,
                                                    const _Float16* __restrict__ xih,
                                                    const float* __restrict__ dbl,
                                                    const _Float16* __restrict__ zh,
                                                    const float* __restrict__ A_log,
                                                    const float* __restrict__ Dp,
                                                    const _Float16* __restrict__ hinit,
                                                    _Float16* __restrict__ yh)
{
    const int tid = threadIdx.x;
    const int d = blockIdx.x * 256 + tid;
    const int c = blockIdx.y, b = blockIdx.z;
    __shared__ float BC[TCH][32];
    const size_t bt0 = (size_t)b * L_ + c * TCH;
    {
        const int tl = tid >> 3;
        const int fo = (tid & 7) * 4;
        *(float4*)&BC[tl][fo] = *(const float4*)&dbl[(bt0 + tl) * 64 + DTR + fo];
    }
    const float A0 = -expf(A_log[d * DSTATE]) * LOG2E;
    const bool ch = chain_ok(A_log + d * DSTATE, A0);
    const float Dd = Dp[d];
    float h[16];
    {
        const size_t o = (((size_t)b * DI_ + d) * NCH + c) * DSTATE;
        load16h(h, &hinit[o]);
    }
    __syncthreads();

    if (ch) {
        for (int t = 0; t < TCH; ++t) {
            const size_t bt = bt0 + t;
            const float dtv = (float)dth[bt * DI_ + d];
            const float xiv = (float)xih[bt * DI_ + d];
            const float zv  = (float)zh[bt * DI_ + d];
            const float w = dtv * xiv;
            float Bv[16], Cv[16];
#pragma unroll
            for (int n = 0; n < 16; n += 4) {
                *(float4*)&Bv[n] = *(const float4*)&BC[t][n];
                *(float4*)&Cv[n] = *(const float4*)&BC[t][16 + n];
            }
            float pw[16];
            pow_chain16(exp2f(dtv * A0), pw);
            float p = 0.f;
#pragma unroll
            for (int n = 0; n < 16; ++n) {
                h[n] = pw[n] * h[n] + w * Bv[n];
                p += h[n] * Cv[n];
            }
            yh[bt * DI_ + d] = (_Float16)((p + xiv * Dd) * (zv * sigmoidf_(zv)));
        }
    } else {
        float An[16];
#pragma unroll
        for (int n = 0; n < 16; ++n)
            An[n] = -expf(A_log[d * DSTATE + n]) * LOG2E;
        for (int t = 0; t < TCH; ++t) {
            const size_t bt = bt0 + t;
            const float dtv = (float)dth[bt * DI_ + d];
            const float xiv = (float)xih[bt * DI_ + d];
            const float zv  = (float)zh[bt * DI_ + d];
            const float w = dtv * xiv;
            float Bv[16], Cv[16];
#pragma unroll
            for (int n = 0; n < 16; n += 4) {
                *(float4*)&Bv[n] = *(const float4*)&BC[t][n];
                *(float4*)&Cv[n] = *(const float4*)&BC[t][16 + n];
            }
            float p = 0.f;
#pragma unroll
            for (int n = 0; n < 16; ++n) {
                h[n] = exp2f(dtv * An[n]) * h[n] + w * Bv[n];
                p += h[n] * Cv[n];
            }
            yh[bt * DI_ + d] = (_Float16)((p + xiv * Dd) * (zv * sigmoidf_(zv)));
        }
    }
}

// LayerNorm over last dim (512) of the SUM of two fp32 partials (GEMM4 split-K);
// writes fp16 (next layer input) and optional fp32 final output.
__global__ __launch_bounds__(256) void layernorm_k(const float* __restrict__ in01,
                                                   const float* __restrict__ g,
                                                   const float* __restrict__ bta,
                                                   _Float16* __restrict__ outh,
                                                   float* __restrict__ outf)
{
    const int row = blockIdx.x;
    const int tid = threadIdx.x;
    const float* p0 = in01 + (size_t)row * DIM_;
    const float* p1 = in01 + (size_t)M_ * DIM_ + (size_t)row * DIM_;
    const float v0 = p0[tid] + p1[tid];
    const float v1 = p0[tid + 256] + p1[tid + 256];
    float s = v0 + v1, ss = v0 * v0 + v1 * v1;
#pragma unroll
    for (int o = 32; o > 0; o >>= 1) { s += __shfl_down(s, o); ss += __shfl_down(ss, o); }
    __shared__ float red[8];
    const int w = tid >> 6;
    if ((tid & 63) == 0) { red[w] = s; red[4 + w] = ss; }
    __syncthreads();
    if (tid == 0) {
        const float S = red[0] + red[1] + red[2] + red[3];
        const float SS = red[4] + red[5] + red[6] + red[7];
        const float mu = S / DIM_;
        const float var = SS / DIM_ - mu * mu;
        red[0] = mu;
        red[1] = rsqrtf(var + 1e-5f);
    }
    __syncthreads();
    const float mu = red[0], rs = red[1];
    const float o0 = (v0 - mu) * rs * g[tid] + bta[tid];
    const float o1 = (v1 - mu) * rs * g[tid + 256] + bta[tid + 256];
    outh[(size_t)row * DIM_ + tid] = (_Float16)o0;
    outh[(size_t)row * DIM_ + tid + 256] = (_Float16)o1;
    if (outf) {
        outf[(size_t)row * DIM_ + tid] = o0;
        outf[(size_t)row * DIM_ + tid + 256] = o1;
    }
}

extern "C" void kernel_launch(void* const* d_in, const int* in_sizes, int n_in,
                              void* d_out, int out_size, void* d_ws, size_t ws_size,
                              hipStream_t stream)
{
    const float* x    = (const float*)d_in[0];
    const float* Win  = (const float*)d_in[1];
    const float* cw   = (const float*)d_in[2];
    const float* cb   = (const float*)d_in[3];
    const float* Wx   = (const float*)d_in[4];
    const float* Wdt  = (const float*)d_in[5];
    const float* bdt  = (const float*)d_in[6];
    const float* Alog = (const float*)d_in[7];
    const float* Dp   = (const float*)d_in[8];
    const float* Wout = (const float*)d_in[9];
    const float* lng  = (const float*)d_in[10];
    const float* lnb  = (const float*)d_in[11];

    // Workspace layout (~170 MB < 232 MB proven).
    float* ws   = (float*)d_ws;
    float* dbl  = ws;                            // M x 64 f32
    float* pc2  = dbl  + (size_t)M_ * 64;        // 2 x M x 512 f32 (GEMM4 partials)
    float* pc   = pc2;                           // KSP x M x 64 f32 (GEMM2 partials, alias)
    _Float16* hloc  = (_Float16*)(pc2 + (size_t)2 * M_ * DIM_); // B x DI x NCH x 16 f16
    _Float16* prod  = hloc  + (size_t)B_ * DI_ * NCH * DSTATE;
    _Float16* xh    = prod  + (size_t)B_ * DI_ * NCH * DSTATE; // M x 512 f16
    _Float16* yh    = xh    + (size_t)M_ * DIM_;          // M x 1024 f16
    _Float16* xih   = yh    + (size_t)M_ * DI_;           // M x 1024 f16
    _Float16* zh    = xih   + (size_t)M_ * DI_;           // M x 1024 f16 (z-half)
    _Float16* xch   = zh    + (size_t)M_ * DI_;           // M x 1024 f16 (conv input)
    _Float16* dth   = xch   + (size_t)M_ * DI_;           // M x 1024 f16 (dt)
    _Float16* Winh  = dth   + (size_t)M_ * DI_;           // 6 x 2048 x 512 f16
    _Float16* Wouth = Winh  + (size_t)6 * 2 * DI_ * DIM_; // 6 x 512 x 1024 f16
    _Float16* Wxh   = Wouth + (size_t)6 * DIM_ * DI_;     // 6 x 64 x 1024 f16
    _Float16* Wdth  = Wxh   + (size_t)6 * 64 * DI_;       // 6 x 1024 x 32 f16
    _Float16* dblh  = Wdth  + (size_t)6 * DI_ * DTR;      // M x 32 f16

    // one-time conversions
    tofp16_k<<<(M_ * DIM_) / 1024, 256, 0, stream>>>(x, xh, M_ * DIM_);
    tofp16_k<<<(6 * 2 * DI_ * DIM_) / 1024, 256, 0, stream>>>(Win, Winh, 6 * 2 * DI_ * DIM_);
    tofp16_k<<<(6 * DIM_ * DI_) / 1024, 256, 0, stream>>>(Wout, Wouth, 6 * DIM_ * DI_);
    tofp16_k<<<(6 * 64 * DI_) / 1024, 256, 0, stream>>>(Wx, Wxh, 6 * 64 * DI_);
    tofp16_k<<<(6 * DI_ * DTR) / 1024, 256, 0, stream>>>(Wdt, Wdth, 6 * DI_ * DTR);

    for (int l = 0; l < 6; ++l) {
        // xz = xh * Winh^T (M x 2048, K=512): x-half -> xch f16, z-half -> zh f16 [BK=64]
        gemm_f16_nt<1, 64><<<dim3((2 * DI_) / GBN, M_ / GBM), 256, 0, stream>>>(
            xh, DIM_, Winh + (size_t)l * 2 * DI_ * DIM_, DIM_, nullptr, 0, DIM_, xch, zh);
        // xih = silu(causal_conv(xch) + cb)   [fp16 in/out, 8 d/thread vectorized]
        conv_silu_k<<<(M_ * DI_) / 2048, 256, 0, stream>>>(
            xch, cw + (size_t)l * DI_ * 4, cb + (size_t)l * DI_, xih);
        // x_dbl = xih * Wxh^T (M x 64, K=1024) [fp16 MFMA, split-K]
        gemm2_f16_splitk<<<dim3(KSP, M_ / 64), 256, 0, stream>>>(
            xih, Wxh + (size_t)l * 64 * DI_, pc);
        gemm2_reduce_k<<<(M_ * 64) / 1024, 256, 0, stream>>>(pc, dbl, dblh);
        // dt = softplus(dblh * Wdth^T + bdt) (M x 1024, K=32) [fp16 MFMA -> fp16 out]
        gemm3_f16<<<dim3(DI_ / 64, M_ / 64), 256, 0, stream>>>(
            dblh, Wdth + (size_t)l * DI_ * DTR, bdt + (size_t)l * DI_, dth);
        // chunked selective scan (register-state, 1 d/thread, exp-chain; fp16 IO)
        scan_chunk_k<<<dim3(DI_ / 256, NCH, B_), 256, 0, stream>>>(
            dth, xih, dbl, Alog + (size_t)l * DI_ * DSTATE, hloc, prod);
        scan_carry_k<<<(B_ * DI_ * DSTATE) / 256, 256, 0, stream>>>(hloc, prod);
        scan_apply_k<<<dim3(DI_ / 256, NCH, B_), 256, 0, stream>>>(
            dth, xih, dbl, zh, Alog + (size_t)l * DI_ * DSTATE, Dp + (size_t)l * DI_, hloc, yh);
        // out partials = yh * Wouth^T (M x 512, K=1024) [fp16 MFMA, split-K=2, BK=32]
        gemm_f16_nt<2, 32><<<dim3(DIM_ / GBN, M_ / GBM, 2), 256, 0, stream>>>(
            yh, DI_, Wouth + (size_t)l * DIM_ * DI_, DI_, pc2, DIM_, 512, nullptr, nullptr);
        // layernorm(sum of partials) -> fp16 next-layer input (+ fp32 final output)
        layernorm_k<<<M_, 256, 0, stream>>>(
            pc2, lng + (size_t)l * DIM_, lnb + (size_t)l * DIM_, xh,
            (l == 5) ? (float*)d_out : nullptr);
    }
}

// Round 20
// 1034.674 us; speedup vs baseline: 1.0162x; 1.0162x over previous
//
#include <hip/hip_runtime.h>
#include <hip/hip_bf16.h>
#include <hip/hip_fp16.h>
#include <cstdint>
#include <cstddef>

// Problem constants
#define B_    4
#define L_    2048
#define DIM_  512
#define DI_   1024          // d_inner
#define M_    (B_ * L_)     // 8192 rows
#define DSTATE 16
#define DTR   32
#define TCH   32            // scan chunk length (proven config)
#define NCH   (L_ / TCH)    // 64 chunks
#define KSP   8             // GEMM2 K-split
#define KCH   (DI_ / KSP)   // 128

typedef __attribute__((ext_vector_type(8))) _Float16 f16x8;   // 8 f16 = 4 VGPRs
typedef __attribute__((ext_vector_type(4))) float f32x4;

#define LOG2E 1.44269504088896340736f

__device__ __forceinline__ float sigmoidf_(float x) { return 1.f / (1.f + expf(-x)); }
__device__ __forceinline__ float softplusf_(float x) { return fmaxf(x, 0.f) + log1pf(expf(-fabsf(x))); }
// fast-trans softplus via HIP device intrinsics (v_exp_f32 / v_log_f32 path)
__device__ __forceinline__ float softplus_fast(float x) {
    return fmaxf(x, 0.f) + __logf(1.f + __expf(-fabsf(x)));
}

// pw[n] = e1^(n+1), n=0..15, via log-depth product tree (15 muls, depth<=5)
__device__ __forceinline__ void pow_chain16(float e1, float* pw) {
    pw[0] = e1;
#pragma unroll
    for (int k = 2; k <= 16; ++k) pw[k - 1] = pw[k / 2 - 1] * pw[k - k / 2 - 1];
}

// fp32 -> fp16 bulk conversion (4 elems/thread)
__global__ __launch_bounds__(256) void tofp16_k(const float* __restrict__ in,
                                                _Float16* __restrict__ out, int n)
{
    const int i = (blockIdx.x * 256 + threadIdx.x) * 4;
    if (i < n) {
        const float4 v = *(const float4*)(in + i);
        _Float16 o[4] = { (_Float16)v.x, (_Float16)v.y, (_Float16)v.z, (_Float16)v.w };
        *(ushort4*)(out + i) = *(const ushort4*)o;
    }
}

// ---- fp16 MFMA GEMM, BK=64 (best measured: round-18 config).
// SPLIT=1 (GEMM1, N=2048): cols < DI_ -> fp16 Cx, cols >= DI_ -> fp16 Cz at col-DI_.
// SPLIT=2 (GEMM4, split-K=2): blockIdx.z = ks selects K-half; fp32 partial to
//   C + ks*M_*DIM_. XCD-aware swizzle on x-y (nwg % 8 == 0 for both uses).
// Staging: 16 chunks of 1024 B per tile; chunk c covers 8 rows x 128 B.
//   Wave wv stages chunks wv*4..wv*4+3; lane l -> row c*8+(l>>3), k-elem (l&7)*8.
#define GBM 128
#define GBN 128
#define GBK 64
template <int SPLIT>
__global__ __launch_bounds__(256) void gemm_f16_nt(const _Float16* __restrict__ A, int lda,
                                                   const _Float16* __restrict__ W, int ldw,
                                                   float* __restrict__ C, int ldc, int K,
                                                   _Float16* __restrict__ Cx,
                                                   _Float16* __restrict__ Cz)
{
    __shared__ _Float16 As[GBM][GBK];   // 16 KB
    __shared__ _Float16 Ws[GBN][GBK];   // 16 KB
    const int tid = threadIdx.x;
    const int wv = tid >> 6, ln = tid & 63;

    if (SPLIT == 2) {
        const int ks = blockIdx.z;
        A += (size_t)ks * 512;            // k-offset within row (lda unchanged)
        W += (size_t)ks * 512;
        C += (size_t)ks * (size_t)M_ * DIM_;
    }

    // XCD swizzle: contiguous chunk of flattened block ids per XCD (L2 locality)
    const int gx = gridDim.x;
    const int nwg = gx * gridDim.y;
    int bid = blockIdx.y * gx + blockIdx.x;
    bid = (bid & 7) * (nwg >> 3) + (bid >> 3);
    const int bx = bid % gx, by = bid / gx;

    const int m0 = by * GBM, n0 = bx * GBN;
    const int wm = (wv >> 1) * 64, wn = (wv & 1) * 64;

    const int c0 = wv * 4;                     // first chunk for this wave
    const int srow0 = c0 * 8 + (ln >> 3);      // row within tile for chunk c0
    const int skcol = (ln & 7) * 8;            // k-elem offset within row

    const int fr = ln & 15;
    const int fk = (ln >> 4) * 8;

    f32x4 acc[4][4] = {};

    for (int k0 = 0; k0 < K; k0 += GBK) {
#pragma unroll
        for (int i = 0; i < 4; ++i) {
            const int c = c0 + i;
            const int row = srow0 + i * 8;
            __builtin_amdgcn_global_load_lds(
                (const __attribute__((address_space(1))) void*)(A + (size_t)(m0 + row) * lda + k0 + skcol),
                (__attribute__((address_space(3))) void*)((char*)&As[0][0] + c * 1024), 16, 0, 0);
            __builtin_amdgcn_global_load_lds(
                (const __attribute__((address_space(1))) void*)(W + (size_t)(n0 + row) * ldw + k0 + skcol),
                (__attribute__((address_space(3))) void*)((char*)&Ws[0][0] + c * 1024), 16, 0, 0);
        }
        __syncthreads();

#pragma unroll
        for (int kk = 0; kk < GBK; kk += 32) {
            f16x8 aF[4], bF[4];
#pragma unroll
            for (int m = 0; m < 4; ++m) aF[m] = *(const f16x8*)&As[wm + m * 16 + fr][kk + fk];
#pragma unroll
            for (int n = 0; n < 4; ++n) bF[n] = *(const f16x8*)&Ws[wn + n * 16 + fr][kk + fk];
#pragma unroll
            for (int m = 0; m < 4; ++m)
#pragma unroll
                for (int n = 0; n < 4; ++n)
                    acc[m][n] = __builtin_amdgcn_mfma_f32_16x16x32_f16(aF[m], bF[n], acc[m][n], 0, 0, 0);
        }
        __syncthreads();
    }

    const int cr = (ln >> 4) * 4;
    const int cc = ln & 15;
#pragma unroll
    for (int m = 0; m < 4; ++m)
#pragma unroll
        for (int n = 0; n < 4; ++n)
#pragma unroll
            for (int r = 0; r < 4; ++r) {
                const int mm = m0 + wm + m * 16 + cr + r;
                const int nn = n0 + wn + n * 16 + cc;
                if (SPLIT == 1) {
                    if (n0 < DI_) Cx[(size_t)mm * DI_ + nn] = (_Float16)acc[m][n][r];
                    else          Cz[(size_t)mm * DI_ + (nn - DI_)] = (_Float16)acc[m][n][r];
                } else {
                    C[(size_t)mm * ldc + nn] = acc[m][n][r];
                }
            }
}

// ---- GEMM2 split-K: P[ks][M][64] = xih[M x 1024] * Wx[64 x 1024]^T over K-chunk ks.
__global__ __launch_bounds__(256) void gemm2_f16_splitk(const _Float16* __restrict__ A,
                                                        const _Float16* __restrict__ W,
                                                        float* __restrict__ P)
{
    __shared__ _Float16 As[64][32];   // 4 KB
    __shared__ _Float16 Ws[64][32];   // 4 KB
    const int tid = threadIdx.x;
    const int wv = tid >> 6, ln = tid & 63;
    const int ks = blockIdx.x;
    const int m0 = blockIdx.y * 64;
    const int srow = wv * 16 + (ln >> 2);
    const int skcol = (ln & 3) * 8;
    const int fr = ln & 15, fk = (ln >> 4) * 8;
    f32x4 acc[4] = {};

    for (int k0 = ks * KCH; k0 < ks * KCH + KCH; k0 += 32) {
        __builtin_amdgcn_global_load_lds(
            (const __attribute__((address_space(1))) void*)(A + (size_t)(m0 + srow) * DI_ + k0 + skcol),
            (__attribute__((address_space(3))) void*)((char*)&As[0][0] + wv * 1024), 16, 0, 0);
        __builtin_amdgcn_global_load_lds(
            (const __attribute__((address_space(1))) void*)(W + (size_t)srow * DI_ + k0 + skcol),
            (__attribute__((address_space(3))) void*)((char*)&Ws[0][0] + wv * 1024), 16, 0, 0);
        __syncthreads();
        const f16x8 aF = *(const f16x8*)&As[wv * 16 + fr][fk];
#pragma unroll
        for (int nf = 0; nf < 4; ++nf) {
            const f16x8 bF = *(const f16x8*)&Ws[nf * 16 + fr][fk];
            acc[nf] = __builtin_amdgcn_mfma_f32_16x16x32_f16(aF, bF, acc[nf], 0, 0, 0);
        }
        __syncthreads();
    }

    const int cr = (ln >> 4) * 4, cc = ln & 15;
    float* Pb = P + (size_t)ks * M_ * 64;
#pragma unroll
    for (int nf = 0; nf < 4; ++nf)
#pragma unroll
        for (int r = 0; r < 4; ++r)
            Pb[(size_t)(m0 + wv * 16 + cr + r) * 64 + nf * 16 + cc] = acc[nf][r];
}

// Fixed-order partial reduction: dbl = sum_ks P[ks]; dt-rank half also as fp16.
__global__ __launch_bounds__(256) void gemm2_reduce_k(const float* __restrict__ P,
                                                      float* __restrict__ dbl,
                                                      _Float16* __restrict__ dblh)
{
    const int i = (blockIdx.x * 256 + threadIdx.x) * 4;  // over M_*64
    float4 s = *(const float4*)&P[i];
#pragma unroll
    for (int ks = 1; ks < KSP; ++ks) {
        const float4 v = *(const float4*)&P[(size_t)ks * M_ * 64 + i];
        s.x += v.x; s.y += v.y; s.z += v.z; s.w += v.w;
    }
    *(float4*)&dbl[i] = s;
    const int col = i & 63;
    if (col < DTR) {
        const int row = i >> 6;
        _Float16 o[4] = { (_Float16)s.x, (_Float16)s.y, (_Float16)s.z, (_Float16)s.w };
        *(ushort4*)&dblh[(size_t)row * DTR + col] = *(const ushort4*)o;
    }
}

// ---- GEMM3 fp16 MFMA: dth[M x 1024] = softplus(dblh[M x 32] * Wdth^T + bdt), fp16 out.
__global__ __launch_bounds__(256) void gemm3_f16(const _Float16* __restrict__ A,
                                                 const _Float16* __restrict__ W,
                                                 const float* __restrict__ bias,
                                                 _Float16* __restrict__ Cout)
{
    __shared__ _Float16 As[64][32];   // 4 KB
    __shared__ _Float16 Ws[64][32];   // 4 KB
    const int tid = threadIdx.x;
    const int wv = tid >> 6, ln = tid & 63;
    const int m0 = blockIdx.y * 64, n0 = blockIdx.x * 64;
    const int srow = wv * 16 + (ln >> 2);
    const int skcol = (ln & 3) * 8;
    const int fr = ln & 15, fk = (ln >> 4) * 8;

    __builtin_amdgcn_global_load_lds(
        (const __attribute__((address_space(1))) void*)(A + (size_t)(m0 + srow) * DTR + skcol),
        (__attribute__((address_space(3))) void*)((char*)&As[0][0] + wv * 1024), 16, 0, 0);
    __builtin_amdgcn_global_load_lds(
        (const __attribute__((address_space(1))) void*)(W + (size_t)(n0 + srow) * DTR + skcol),
        (__attribute__((address_space(3))) void*)((char*)&Ws[0][0] + wv * 1024), 16, 0, 0);
    __syncthreads();

    const f16x8 aF = *(const f16x8*)&As[wv * 16 + fr][fk];
    f32x4 acc[4] = {};
#pragma unroll
    for (int nf = 0; nf < 4; ++nf) {
        const f16x8 bF = *(const f16x8*)&Ws[nf * 16 + fr][fk];
        acc[nf] = __builtin_amdgcn_mfma_f32_16x16x32_f16(aF, bF, acc[nf], 0, 0, 0);
    }

    const int cr = (ln >> 4) * 4, cc = ln & 15;
    const int mmb = m0 + wv * 16 + cr;
#pragma unroll
    for (int nf = 0; nf < 4; ++nf) {
        const int nn = n0 + nf * 16 + cc;
        const float bs = bias[nn];
#pragma unroll
        for (int r = 0; r < 4; ++r)
            Cout[(size_t)(mmb + r) * DI_ + nn] = (_Float16)softplus_fast(acc[nf][r] + bs);
    }
}

// depthwise causal conv(4) + bias + SiLU, vectorized: 8 consecutive d per thread.
__global__ __launch_bounds__(256) void conv_silu_k(const _Float16* __restrict__ xch,
                                                   const float* __restrict__ cw,
                                                   const float* __restrict__ cb,
                                                   _Float16* __restrict__ xih)
{
    const int idx = (blockIdx.x * 256 + threadIdx.x) * 8;   // over M_*DI_
    const int d0  = idx & (DI_ - 1);
    const int bt  = idx >> 10;                               // b*L + t
    const int t   = bt & (L_ - 1);

    float xr[4][8];
#pragma unroll
    for (int j = 0; j < 4; ++j) {
        const int tt = t - 3 + j;
        if (tt >= 0) {
            const f16x8 xv = *(const f16x8*)&xch[(size_t)(bt - 3 + j) * DI_ + d0];
#pragma unroll
            for (int i = 0; i < 8; ++i) xr[j][i] = (float)xv[i];
        } else {
#pragma unroll
            for (int i = 0; i < 8; ++i) xr[j][i] = 0.f;
        }
    }

    _Float16 o[8];
#pragma unroll
    for (int i = 0; i < 8; ++i) {
        const float4 w = *(const float4*)&cw[(size_t)(d0 + i) * 4];
        float a = cb[d0 + i] + w.x * xr[0][i] + w.y * xr[1][i]
                             + w.z * xr[2][i] + w.w * xr[3][i];
        o[i] = (_Float16)(a * sigmoidf_(a));
    }
    *(f16x8*)&xih[idx] = *(const f16x8*)&o[0];
}

// ---- Chunked parallel scan, register-state, 1 channel per thread ---------
__device__ __forceinline__ bool chain_ok(const float* Arow, float A0l2) {
    bool ok = true;
#pragma unroll
    for (int n = 1; n < 16; ++n) {
        const float an = -expf(Arow[n]) * LOG2E;
        ok = ok && (fabsf(an - (float)(n + 1) * A0l2) <= 1e-4f * fabsf(an));
    }
    return ok;
}

__device__ __forceinline__ void store16h(_Float16* dst, const float* src) {
    _Float16 t[16];
#pragma unroll
    for (int n = 0; n < 16; ++n) t[n] = (_Float16)src[n];
    *(f16x8*)&dst[0] = *(const f16x8*)&t[0];
    *(f16x8*)&dst[8] = *(const f16x8*)&t[8];
}
__device__ __forceinline__ void load16h(float* dst, const _Float16* src) {
    _Float16 t[16];
    *(f16x8*)&t[0] = *(const f16x8*)&src[0];
    *(f16x8*)&t[8] = *(const f16x8*)&src[8];
#pragma unroll
    for (int n = 0; n < 16; ++n) dst[n] = (float)t[n];
}

__global__ __launch_bounds__(256) void scan_chunk_k(const _Float16* __restrict__ dth,
                                                    const _Float16* __restrict__ xih,
                                                    const float* __restrict__ dbl,
                                                    const float* __restrict__ A_log,
                                                    _Float16* __restrict__ hloc,
                                                    _Float16* __restrict__ prod)
{
    const int tid = threadIdx.x;
    const int d = blockIdx.x * 256 + tid;
    const int c = blockIdx.y, b = blockIdx.z;
    __shared__ float BC[TCH][32];
    const size_t bt0 = (size_t)b * L_ + c * TCH;
    {   // stage TCH rows x 32 floats (256 threads cover 32x8 float4s)
        const int tl = tid >> 3;
        const int fo = (tid & 7) * 4;
        *(float4*)&BC[tl][fo] = *(const float4*)&dbl[(bt0 + tl) * 64 + DTR + fo];
    }
    const float A0 = -expf(A_log[d * DSTATE]) * LOG2E;
    const bool ch = chain_ok(A_log + d * DSTATE, A0);
    __syncthreads();

    float h[16] = {};
    float sdt = 0.f;
    if (ch) {
        for (int t = 0; t < TCH; ++t) {
            const size_t bt = bt0 + t;
            const float dtv = (float)dth[bt * DI_ + d];
            const float xiv = (float)xih[bt * DI_ + d];
            const float w = dtv * xiv;
            sdt += dtv;
            float Bv[16];
#pragma unroll
            for (int n = 0; n < 16; n += 4) *(float4*)&Bv[n] = *(const float4*)&BC[t][n];
            float pw[16];
            pow_chain16(exp2f(dtv * A0), pw);
#pragma unroll
            for (int n = 0; n < 16; ++n)
                h[n] = pw[n] * h[n] + w * Bv[n];
        }
        const size_t o = (((size_t)b * DI_ + d) * NCH + c) * DSTATE;
        float e[16];
        pow_chain16(exp2f(A0 * sdt), e);
        store16h(&hloc[o], h); store16h(&prod[o], e);
    } else {
        float An[16];
#pragma unroll
        for (int n = 0; n < 16; ++n)
            An[n] = -expf(A_log[d * DSTATE + n]) * LOG2E;
        for (int t = 0; t < TCH; ++t) {
            const size_t bt = bt0 + t;
            const float dtv = (float)dth[bt * DI_ + d];
            const float xiv = (float)xih[bt * DI_ + d];
            const float w = dtv * xiv;
            sdt += dtv;
            float Bv[16];
#pragma unroll
            for (int n = 0; n < 16; n += 4) *(float4*)&Bv[n] = *(const float4*)&BC[t][n];
#pragma unroll
            for (int n = 0; n < 16; ++n)
                h[n] = exp2f(dtv * An[n]) * h[n] + w * Bv[n];
        }
        const size_t o = (((size_t)b * DI_ + d) * NCH + c) * DSTATE;
        float e[16];
#pragma unroll
        for (int n = 0; n < 16; ++n) e[n] = exp2f(An[n] * sdt);
        store16h(&hloc[o], h); store16h(&prod[o], e);
    }
}

// Phase 2: sequential combine over chunks, 4-deep load pipelining (fp16 IO, fp32 math).
__global__ __launch_bounds__(256) void scan_carry_k(_Float16* __restrict__ hloc,
                                                    const _Float16* __restrict__ prod)
{
    const int idx = blockIdx.x * 256 + threadIdx.x;  // over B_*DI_*DSTATE
    const int n = idx & 15;
    const int d = (idx >> 4) & (DI_ - 1);
    const int b = idx >> 14;
    const size_t base = (((size_t)b * DI_ + d) * NCH) * DSTATE + n;
    float hl[4], pr[4], hn[4], pn[4];
#pragma unroll
    for (int j = 0; j < 4; ++j) {
        hl[j] = (float)hloc[base + (size_t)j * DSTATE];
        pr[j] = (float)prod[base + (size_t)j * DSTATE];
    }
    float carry = 0.f;
    for (int c0 = 0; c0 < NCH; c0 += 4) {
        if (c0 + 4 < NCH) {
#pragma unroll
            for (int j = 0; j < 4; ++j) {
                hn[j] = (float)hloc[base + (size_t)(c0 + 4 + j) * DSTATE];
                pn[j] = (float)prod[base + (size_t)(c0 + 4 + j) * DSTATE];
            }
        }
#pragma unroll
        for (int j = 0; j < 4; ++j) {
            hloc[base + (size_t)(c0 + j) * DSTATE] = (_Float16)carry;
            carry = hl[j] + pr[j] * carry;
        }
#pragma unroll
        for (int j = 0; j < 4; ++j) { hl[j] = hn[j]; pr[j] = pn[j]; }
    }
}

// Phase 3: re-scan from true initial state; y = (h·C + xi*D)*silu(z) as fp16.
__global__ __launch_bounds__(256) void scan_apply_k(const _Float16* __restrict__ dth,
                                                    const _Float16* __restrict__ xih,
                                                    const float* __restrict__ dbl,
                                                    const _Float16* __restrict__ zh,
                                                    const float* __restrict__ A_log,
                                                    const float* __restrict__ Dp,
                                                    const _Float16* __restrict__ hinit,
                                                    _Float16* __restrict__ yh)
{
    const int tid = threadIdx.x;
    const int d = blockIdx.x * 256 + tid;
    const int c = blockIdx.y, b = blockIdx.z;
    __shared__ float BC[TCH][32];
    const size_t bt0 = (size_t)b * L_ + c * TCH;
    {
        const int tl = tid >> 3;
        const int fo = (tid & 7) * 4;
        *(float4*)&BC[tl][fo] = *(const float4*)&dbl[(bt0 + tl) * 64 + DTR + fo];
    }
    const float A0 = -expf(A_log[d * DSTATE]) * LOG2E;
    const bool ch = chain_ok(A_log + d * DSTATE, A0);
    const float Dd = Dp[d];
    float h[16];
    {
        const size_t o = (((size_t)b * DI_ + d) * NCH + c) * DSTATE;
        load16h(h, &hinit[o]);
    }
    __syncthreads();

    if (ch) {
        for (int t = 0; t < TCH; ++t) {
            const size_t bt = bt0 + t;
            const float dtv = (float)dth[bt * DI_ + d];
            const float xiv = (float)xih[bt * DI_ + d];
            const float zv  = (float)zh[bt * DI_ + d];
            const float w = dtv * xiv;
            float Bv[16], Cv[16];
#pragma unroll
            for (int n = 0; n < 16; n += 4) {
                *(float4*)&Bv[n] = *(const float4*)&BC[t][n];
                *(float4*)&Cv[n] = *(const float4*)&BC[t][16 + n];
            }
            float pw[16];
            pow_chain16(exp2f(dtv * A0), pw);
            float p = 0.f;
#pragma unroll
            for (int n = 0; n < 16; ++n) {
                h[n] = pw[n] * h[n] + w * Bv[n];
                p += h[n] * Cv[n];
            }
            yh[bt * DI_ + d] = (_Float16)((p + xiv * Dd) * (zv * sigmoidf_(zv)));
        }
    } else {
        float An[16];
#pragma unroll
        for (int n = 0; n < 16; ++n)
            An[n] = -expf(A_log[d * DSTATE + n]) * LOG2E;
        for (int t = 0; t < TCH; ++t) {
            const size_t bt = bt0 + t;
            const float dtv = (float)dth[bt * DI_ + d];
            const float xiv = (float)xih[bt * DI_ + d];
            const float zv  = (float)zh[bt * DI_ + d];
            const float w = dtv * xiv;
            float Bv[16], Cv[16];
#pragma unroll
            for (int n = 0; n < 16; n += 4) {
                *(float4*)&Bv[n] = *(const float4*)&BC[t][n];
                *(float4*)&Cv[n] = *(const float4*)&BC[t][16 + n];
            }
            float p = 0.f;
#pragma unroll
            for (int n = 0; n < 16; ++n) {
                h[n] = exp2f(dtv * An[n]) * h[n] + w * Bv[n];
                p += h[n] * Cv[n];
            }
            yh[bt * DI_ + d] = (_Float16)((p + xiv * Dd) * (zv * sigmoidf_(zv)));
        }
    }
}

// LayerNorm over last dim (512) of the SUM of two fp32 partials (GEMM4 split-K);
// writes fp16 (next layer input) and optional fp32 final output.
__global__ __launch_bounds__(256) void layernorm_k(const float* __restrict__ in01,
                                                   const float* __restrict__ g,
                                                   const float* __restrict__ bta,
                                                   _Float16* __restrict__ outh,
                                                   float* __restrict__ outf)
{
    const int row = blockIdx.x;
    const int tid = threadIdx.x;
    const float* p0 = in01 + (size_t)row * DIM_;
    const float* p1 = in01 + (size_t)M_ * DIM_ + (size_t)row * DIM_;
    const float v0 = p0[tid] + p1[tid];
    const float v1 = p0[tid + 256] + p1[tid + 256];
    float s = v0 + v1, ss = v0 * v0 + v1 * v1;
#pragma unroll
    for (int o = 32; o > 0; o >>= 1) { s += __shfl_down(s, o); ss += __shfl_down(ss, o); }
    __shared__ float red[8];
    const int w = tid >> 6;
    if ((tid & 63) == 0) { red[w] = s; red[4 + w] = ss; }
    __syncthreads();
    if (tid == 0) {
        const float S = red[0] + red[1] + red[2] + red[3];
        const float SS = red[4] + red[5] + red[6] + red[7];
        const float mu = S / DIM_;
        const float var = SS / DIM_ - mu * mu;
        red[0] = mu;
        red[1] = rsqrtf(var + 1e-5f);
    }
    __syncthreads();
    const float mu = red[0], rs = red[1];
    const float o0 = (v0 - mu) * rs * g[tid] + bta[tid];
    const float o1 = (v1 - mu) * rs * g[tid + 256] + bta[tid + 256];
    outh[(size_t)row * DIM_ + tid] = (_Float16)o0;
    outh[(size_t)row * DIM_ + tid + 256] = (_Float16)o1;
    if (outf) {
        outf[(size_t)row * DIM_ + tid] = o0;
        outf[(size_t)row * DIM_ + tid + 256] = o1;
    }
}

extern "C" void kernel_launch(void* const* d_in, const int* in_sizes, int n_in,
                              void* d_out, int out_size, void* d_ws, size_t ws_size,
                              hipStream_t stream)
{
    const float* x    = (const float*)d_in[0];
    const float* Win  = (const float*)d_in[1];
    const float* cw   = (const float*)d_in[2];
    const float* cb   = (const float*)d_in[3];
    const float* Wx   = (const float*)d_in[4];
    const float* Wdt  = (const float*)d_in[5];
    const float* bdt  = (const float*)d_in[6];
    const float* Alog = (const float*)d_in[7];
    const float* Dp   = (const float*)d_in[8];
    const float* Wout = (const float*)d_in[9];
    const float* lng  = (const float*)d_in[10];
    const float* lnb  = (const float*)d_in[11];

    // Workspace layout (~170 MB < 232 MB proven).
    float* ws   = (float*)d_ws;
    float* dbl  = ws;                            // M x 64 f32
    float* pc2  = dbl  + (size_t)M_ * 64;        // 2 x M x 512 f32 (GEMM4 partials)
    float* pc   = pc2;                           // KSP x M x 64 f32 (GEMM2 partials, alias)
    _Float16* hloc  = (_Float16*)(pc2 + (size_t)2 * M_ * DIM_); // B x DI x NCH x 16 f16
    _Float16* prod  = hloc  + (size_t)B_ * DI_ * NCH * DSTATE;
    _Float16* xh    = prod  + (size_t)B_ * DI_ * NCH * DSTATE; // M x 512 f16
    _Float16* yh    = xh    + (size_t)M_ * DIM_;          // M x 1024 f16
    _Float16* xih   = yh    + (size_t)M_ * DI_;           // M x 1024 f16
    _Float16* zh    = xih   + (size_t)M_ * DI_;           // M x 1024 f16 (z-half)
    _Float16* xch   = zh    + (size_t)M_ * DI_;           // M x 1024 f16 (conv input)
    _Float16* dth   = xch   + (size_t)M_ * DI_;           // M x 1024 f16 (dt)
    _Float16* Winh  = dth   + (size_t)M_ * DI_;           // 6 x 2048 x 512 f16
    _Float16* Wouth = Winh  + (size_t)6 * 2 * DI_ * DIM_; // 6 x 512 x 1024 f16
    _Float16* Wxh   = Wouth + (size_t)6 * DIM_ * DI_;     // 6 x 64 x 1024 f16
    _Float16* Wdth  = Wxh   + (size_t)6 * 64 * DI_;       // 6 x 1024 x 32 f16
    _Float16* dblh  = Wdth  + (size_t)6 * DI_ * DTR;      // M x 32 f16

    // one-time conversions
    tofp16_k<<<(M_ * DIM_) / 1024, 256, 0, stream>>>(x, xh, M_ * DIM_);
    tofp16_k<<<(6 * 2 * DI_ * DIM_) / 1024, 256, 0, stream>>>(Win, Winh, 6 * 2 * DI_ * DIM_);
    tofp16_k<<<(6 * DIM_ * DI_) / 1024, 256, 0, stream>>>(Wout, Wouth, 6 * DIM_ * DI_);
    tofp16_k<<<(6 * 64 * DI_) / 1024, 256, 0, stream>>>(Wx, Wxh, 6 * 64 * DI_);
    tofp16_k<<<(6 * DI_ * DTR) / 1024, 256, 0, stream>>>(Wdt, Wdth, 6 * DI_ * DTR);

    for (int l = 0; l < 6; ++l) {
        // xz = xh * Winh^T (M x 2048, K=512): x-half -> xch f16, z-half -> zh f16
        gemm_f16_nt<1><<<dim3((2 * DI_) / GBN, M_ / GBM), 256, 0, stream>>>(
            xh, DIM_, Winh + (size_t)l * 2 * DI_ * DIM_, DIM_, nullptr, 0, DIM_, xch, zh);
        // xih = silu(causal_conv(xch) + cb)   [fp16 in/out, 8 d/thread vectorized]
        conv_silu_k<<<(M_ * DI_) / 2048, 256, 0, stream>>>(
            xch, cw + (size_t)l * DI_ * 4, cb + (size_t)l * DI_, xih);
        // x_dbl = xih * Wxh^T (M x 64, K=1024) [fp16 MFMA, split-K]
        gemm2_f16_splitk<<<dim3(KSP, M_ / 64), 256, 0, stream>>>(
            xih, Wxh + (size_t)l * 64 * DI_, pc);
        gemm2_reduce_k<<<(M_ * 64) / 1024, 256, 0, stream>>>(pc, dbl, dblh);
        // dt = softplus(dblh * Wdth^T + bdt) (M x 1024, K=32) [fp16 MFMA -> fp16 out]
        gemm3_f16<<<dim3(DI_ / 64, M_ / 64), 256, 0, stream>>>(
            dblh, Wdth + (size_t)l * DI_ * DTR, bdt + (size_t)l * DI_, dth);
        // chunked selective scan (register-state, 1 d/thread, exp-chain; fp16 IO)
        scan_chunk_k<<<dim3(DI_ / 256, NCH, B_), 256, 0, stream>>>(
            dth, xih, dbl, Alog + (size_t)l * DI_ * DSTATE, hloc, prod);
        scan_carry_k<<<(B_ * DI_ * DSTATE) / 256, 256, 0, stream>>>(hloc, prod);
        scan_apply_k<<<dim3(DI_ / 256, NCH, B_), 256, 0, stream>>>(
            dth, xih, dbl, zh, Alog + (size_t)l * DI_ * DSTATE, Dp + (size_t)l * DI_, hloc, yh);
        // out partials = yh * Wouth^T (M x 512, K=1024) [fp16 MFMA, split-K=2]
        gemm_f16_nt<2><<<dim3(DIM_ / GBN, M_ / GBM, 2), 256, 0, stream>>>(
            yh, DI_, Wouth + (size_t)l * DIM_ * DI_, DI_, pc2, DIM_, 512, nullptr, nullptr);
        // layernorm(sum of partials) -> fp16 next-layer input (+ fp32 final output)
        layernorm_k<<<M_, 256, 0, stream>>>(
            pc2, lng + (size_t)l * DIM_, lnb + (size_t)l * DIM_, xh,
            (l == 5) ? (float*)d_out : nullptr);
    }
}